// Round 1
// baseline (505.502 us; speedup 1.0000x reference)
//
#include <hip/hip_runtime.h>
#include <hip/hip_bf16.h>

typedef unsigned short u16;
typedef unsigned int   u32;
typedef __attribute__((ext_vector_type(4))) float f32x4;
typedef __attribute__((ext_vector_type(8))) short s16x8;

#define DI __device__ __forceinline__

static constexpr int Bb = 2, Ss = 2048, Hh = 16, Dd = 64, Ee = 1024;
static constexpr int Mrows = Bb * Ss;          // 4096
static constexpr size_t NE = (size_t)Mrows * Ee;   // 4 M elems
static constexpr size_t WN = (size_t)Ee * Ee;      // 1 M elems

DI float bf2f(u16 h) { u32 u = ((u32)h) << 16; return __builtin_bit_cast(float, u); }
DI u16 f2bf(float f) {
    u32 u = __builtin_bit_cast(u32, f);
    u32 r = (u + 0x7FFFu + ((u >> 16) & 1u)) >> 16;
    return (u16)r;
}

#define MFMA(a, b, c) __builtin_amdgcn_mfma_f32_16x16x32_bf16((a), (b), (c), 0, 0, 0)

// ---------------- prep: fp32 -> bf16 hi (+ optional lo residual) ----------------
__global__ __launch_bounds__(256) void k_split(const float* __restrict__ x,
                                               u16* __restrict__ h, u16* __restrict__ l, int n) {
    int i = blockIdx.x * 256 + threadIdx.x;
    if (i >= n) return;
    float v = x[i];
    u16 hh = f2bf(v);
    h[i] = hh;
    if (l) l[i] = f2bf(v - bf2f(hh));
}

// ---------------- prep: weights -> B^T form [N][K], bf16 hi (+lo) ----------------
// stacked=1: W is [H][E][D], logical col n = h*64+d, k = e  -> src (n>>6)*E*D + k*D + (n&63)
// stacked=0: W is [E][E] row-major [k][n]                   -> src k*E + n
__global__ __launch_bounds__(256) void k_wT(const float* __restrict__ W,
                                            u16* __restrict__ h, u16* __restrict__ l, int stacked) {
    int idx = blockIdx.x * 256 + threadIdx.x;   // n*1024 + k
    if (idx >= (int)WN) return;
    int n = idx >> 10, k = idx & 1023;
    float v = stacked ? W[(size_t)(n >> 6) * (Ee * Dd) + (size_t)k * Dd + (n & 63)]
                      : W[(size_t)k * Ee + n];
    u16 hh = f2bf(v);
    h[idx] = hh;
    if (l) l[idx] = f2bf(v - bf2f(hh));
}

// ---------------- GEMM: C[M][N] = A[M][K] * B^T[N][K] + bias[n] ----------------
// SPLIT=1: A,B have hi/lo, accumulate AhBh + AhBl + AlBh (fp32-ish precision)
// OUTMODE: 0 = fp32 row-major, 1 = bf16 transposed [N][M] (for Vt), 2 = bf16 hi/lo row-major
template <int SPLIT, int OUTMODE>
__global__ __launch_bounds__(256) void k_gemm(
    const u16* __restrict__ Ah, const u16* __restrict__ Al,
    const u16* __restrict__ Bh, const u16* __restrict__ Bl,
    const float* __restrict__ bias,
    u16* __restrict__ C16h, u16* __restrict__ C16l, float* __restrict__ Cf,
    int M, int N, int K) {
    constexpr int NB = SPLIT ? 2 : 1;
    __shared__ u16 As[NB][128 * 32];
    __shared__ u16 Bs[NB][128 * 32];

    const int tid = threadIdx.x;
    const int wave = tid >> 6, lane = tid & 63;
    const int quad = lane >> 4, l16 = lane & 15;
    const int m0 = blockIdx.y * 128, n0 = blockIdx.x * 128;
    const int wm = (wave >> 1) * 64, wn = (wave & 1) * 64;

    f32x4 acc[4][4];
#pragma unroll
    for (int i = 0; i < 4; i++)
#pragma unroll
        for (int j = 0; j < 4; j++) acc[i][j] = (f32x4)0.0f;

    for (int kk = 0; kk < K; kk += 32) {
        __syncthreads();
#pragma unroll
        for (int i = 0; i < 2; i++) {
            int c = tid + i * 256;            // 512 chunks of 8 elems (16B)
            int row = c >> 2, c8 = (c & 3) * 8;
            size_t ga = (size_t)(m0 + row) * K + kk + c8;
            size_t gb = (size_t)(n0 + row) * K + kk + c8;
            ((s16x8*)&As[0][0])[c] = *(const s16x8*)(Ah + ga);
            ((s16x8*)&Bs[0][0])[c] = *(const s16x8*)(Bh + gb);
            if constexpr (SPLIT) {
                ((s16x8*)&As[1][0])[c] = *(const s16x8*)(Al + ga);
                ((s16x8*)&Bs[1][0])[c] = *(const s16x8*)(Bl + gb);
            }
        }
        __syncthreads();

        s16x8 af[4][2], bf[4][2];
#pragma unroll
        for (int mt = 0; mt < 4; mt++) {
            int r = wm + mt * 16 + l16;
            af[mt][0] = *(const s16x8*)&As[0][r * 32 + quad * 8];
            if constexpr (SPLIT) af[mt][1] = *(const s16x8*)&As[1][r * 32 + quad * 8];
        }
#pragma unroll
        for (int nt = 0; nt < 4; nt++) {
            int r = wn + nt * 16 + l16;
            bf[nt][0] = *(const s16x8*)&Bs[0][r * 32 + quad * 8];
            if constexpr (SPLIT) bf[nt][1] = *(const s16x8*)&Bs[1][r * 32 + quad * 8];
        }
#pragma unroll
        for (int mt = 0; mt < 4; mt++)
#pragma unroll
            for (int nt = 0; nt < 4; nt++) {
                acc[mt][nt] = MFMA(af[mt][0], bf[nt][0], acc[mt][nt]);
                if constexpr (SPLIT) {
                    acc[mt][nt] = MFMA(af[mt][0], bf[nt][1], acc[mt][nt]);
                    acc[mt][nt] = MFMA(af[mt][1], bf[nt][0], acc[mt][nt]);
                }
            }
    }

    // epilogue — C/D layout: col = lane&15, row = quad*4 + reg
#pragma unroll
    for (int mt = 0; mt < 4; mt++)
#pragma unroll
        for (int nt = 0; nt < 4; nt++)
#pragma unroll
            for (int r = 0; r < 4; r++) {
                int gm = m0 + wm + mt * 16 + quad * 4 + r;
                int gn = n0 + wn + nt * 16 + l16;
                float v = acc[mt][nt][r] + bias[gn];
                if constexpr (OUTMODE == 0) {
                    Cf[(size_t)gm * N + gn] = v;
                } else if constexpr (OUTMODE == 2) {
                    u16 hh = f2bf(v);
                    C16h[(size_t)gm * N + gn] = hh;
                    C16l[(size_t)gm * N + gn] = f2bf(v - bf2f(hh));
                } else {
                    C16h[(size_t)gn * M + gm] = f2bf(v);   // transposed (Vt)
                }
            }
}

// ---------------- flash attention per (b,h) ----------------
// Qh/Ql, Kh/Kl: [4096][1024] bf16 hi/lo (head cols h*64..h*64+63)
// Vt: [1024][4096] bf16 (Vt[h*64+d][b*S+t]); ctx out: [4096][1024] bf16
__global__ __launch_bounds__(256) void k_attn(
    const u16* __restrict__ Qh, const u16* __restrict__ Ql,
    const u16* __restrict__ Kh, const u16* __restrict__ Kl,
    const u16* __restrict__ Vt, u16* __restrict__ ctx) {
    const int bh = blockIdx.y;
    const int b = bh >> 4, h = bh & 15;
    const int q0 = blockIdx.x * 64;
    const int rowBase = b * Ss + q0;
    const int hc = h * 64;

    __shared__ u16 Qs[2][64 * 64];
    __shared__ u16 Ks[2][64 * 64];
    __shared__ u16 Vs[64 * 64];        // [d][t]
    __shared__ u16 Ps[4][16 * 64];     // per-wave [m][t]

    const int tid = threadIdx.x;
    const int wave = tid >> 6, lane = tid & 63;
    const int quad = lane >> 4, l16 = lane & 15;

    // stage Q tile (hi/lo): 64 rows x 64 cols
#pragma unroll
    for (int hl = 0; hl < 2; hl++) {
        const u16* g = hl ? Ql : Qh;
#pragma unroll
        for (int i = 0; i < 2; i++) {
            int c = tid + i * 256;             // 512 chunks
            int row = c >> 3, c8 = (c & 7) * 8;
            ((s16x8*)&Qs[hl][0])[c] = *(const s16x8*)(g + (size_t)(rowBase + row) * Ee + hc + c8);
        }
    }

    f32x4 o[4];
#pragma unroll
    for (int i = 0; i < 4; i++) o[i] = (f32x4)0.0f;
    float mrow[4] = {-1e30f, -1e30f, -1e30f, -1e30f};
    float lrow[4] = {0.f, 0.f, 0.f, 0.f};

    for (int t0 = 0; t0 < Ss; t0 += 64) {
        const int kRowBase = b * Ss + t0;
        __syncthreads();
#pragma unroll
        for (int hl = 0; hl < 2; hl++) {
            const u16* g = hl ? Kl : Kh;
#pragma unroll
            for (int i = 0; i < 2; i++) {
                int c = tid + i * 256;
                int row = c >> 3, c8 = (c & 7) * 8;
                ((s16x8*)&Ks[hl][0])[c] = *(const s16x8*)(g + (size_t)(kRowBase + row) * Ee + hc + c8);
            }
        }
#pragma unroll
        for (int i = 0; i < 2; i++) {
            int c = tid + i * 256;
            int d = c >> 3, c8 = (c & 7) * 8;
            ((s16x8*)&Vs[0])[c] = *(const s16x8*)(Vt + (size_t)(hc + d) * Mrows + kRowBase + c8);
        }
        __syncthreads();

        // S = Q K^T (split: QhKh + QhKl + QlKh), wave owns 16 q-rows
        f32x4 sacc[4];
#pragma unroll
        for (int i = 0; i < 4; i++) sacc[i] = (f32x4)0.0f;
        s16x8 aq[2][2];
#pragma unroll
        for (int kc = 0; kc < 2; kc++) {
            aq[kc][0] = *(const s16x8*)&Qs[0][(wave * 16 + l16) * 64 + kc * 32 + quad * 8];
            aq[kc][1] = *(const s16x8*)&Qs[1][(wave * 16 + l16) * 64 + kc * 32 + quad * 8];
        }
#pragma unroll
        for (int nt = 0; nt < 4; nt++) {
#pragma unroll
            for (int kc = 0; kc < 2; kc++) {
                s16x8 bh16 = *(const s16x8*)&Ks[0][(nt * 16 + l16) * 64 + kc * 32 + quad * 8];
                s16x8 bl16 = *(const s16x8*)&Ks[1][(nt * 16 + l16) * 64 + kc * 32 + quad * 8];
                sacc[nt] = MFMA(aq[kc][0], bh16, sacc[nt]);
                sacc[nt] = MFMA(aq[kc][0], bl16, sacc[nt]);
                sacc[nt] = MFMA(aq[kc][1], bh16, sacc[nt]);
            }
        }

        // online softmax (rows m = quad*4+r, cols t = nt*16 + l16)
        float sv[4][4];
#pragma unroll
        for (int nt = 0; nt < 4; nt++)
#pragma unroll
            for (int r = 0; r < 4; r++) sv[nt][r] = sacc[nt][r] * 0.125f;

        float mnew[4], alpha[4];
#pragma unroll
        for (int r = 0; r < 4; r++) {
            float t = fmaxf(fmaxf(sv[0][r], sv[1][r]), fmaxf(sv[2][r], sv[3][r]));
#pragma unroll
            for (int off = 1; off < 16; off <<= 1) t = fmaxf(t, __shfl_xor(t, off));
            mnew[r] = fmaxf(mrow[r], t);
            alpha[r] = __expf(mrow[r] - mnew[r]);
            mrow[r] = mnew[r];
        }
#pragma unroll
        for (int nt = 0; nt < 4; nt++)
#pragma unroll
            for (int r = 0; r < 4; r++) sv[nt][r] = __expf(sv[nt][r] - mnew[r]);
#pragma unroll
        for (int r = 0; r < 4; r++) {
            float s = sv[0][r] + sv[1][r] + sv[2][r] + sv[3][r];
#pragma unroll
            for (int off = 1; off < 16; off <<= 1) s += __shfl_xor(s, off);
            lrow[r] = lrow[r] * alpha[r] + s;
        }
        // write P (bf16) to wave-private LDS, rescale O
#pragma unroll
        for (int nt = 0; nt < 4; nt++)
#pragma unroll
            for (int r = 0; r < 4; r++) {
                Ps[wave][(quad * 4 + r) * 64 + nt * 16 + l16] = f2bf(sv[nt][r]);
                o[nt][r] *= alpha[r];
            }

        // O += P V   (A = P[m][t], B = V[t][d] via Vs[d][t])
#pragma unroll
        for (int kc = 0; kc < 2; kc++) {
            s16x8 ap = *(const s16x8*)&Ps[wave][l16 * 64 + kc * 32 + quad * 8];
#pragma unroll
            for (int nt = 0; nt < 4; nt++) {
                s16x8 bv16 = *(const s16x8*)&Vs[(nt * 16 + l16) * 64 + kc * 32 + quad * 8];
                o[nt] = MFMA(ap, bv16, o[nt]);
            }
        }
        __syncthreads();
    }

    // epilogue: ctx[row][h*64+d] = O/l
#pragma unroll
    for (int nt = 0; nt < 4; nt++)
#pragma unroll
        for (int r = 0; r < 4; r++) {
            int gm = rowBase + wave * 16 + quad * 4 + r;
            int gd = hc + nt * 16 + l16;
            ctx[(size_t)gm * Ee + gd] = f2bf(o[nt][r] / lrow[r]);
        }
}

extern "C" void kernel_launch(void* const* d_in, const int* in_sizes, int n_in,
                              void* d_out, int out_size, void* d_ws, size_t ws_size,
                              hipStream_t stream) {
    const float* q  = (const float*)d_in[0];
    const float* kin = (const float*)d_in[1];
    const float* v  = (const float*)d_in[2];
    const float* Wq = (const float*)d_in[3];
    const float* Wk = (const float*)d_in[4];
    const float* Wv = (const float*)d_in[5];
    const float* bq = (const float*)d_in[6];
    const float* bk = (const float*)d_in[7];
    const float* bv = (const float*)d_in[8];
    const float* Wo = (const float*)d_in[9];
    const float* bo = (const float*)d_in[10];

    u16* ws = (u16*)d_ws;
    u16 *qh = ws,          *ql = ws + NE,     *kh = ws + 2 * NE, *kl = ws + 3 * NE;
    u16 *vh = ws + 4 * NE;
    u16 *Qh = ws + 5 * NE, *Ql = ws + 6 * NE, *Kh = ws + 7 * NE, *Kl = ws + 8 * NE;
    u16 *Vt = ws + 9 * NE, *ctx = ws + 10 * NE;
    u16 *WqTh = ws + 11 * NE;
    u16 *WqTl = WqTh + WN, *WkTh = WqTh + 2 * WN, *WkTl = WqTh + 3 * WN;
    u16 *WvTh = WqTh + 4 * WN, *WoTh = WqTh + 5 * WN;

    dim3 b256(256);
    k_split<<<dim3(NE / 256), b256, 0, stream>>>(q,   qh, ql, (int)NE);
    k_split<<<dim3(NE / 256), b256, 0, stream>>>(kin, kh, kl, (int)NE);
    k_split<<<dim3(NE / 256), b256, 0, stream>>>(v,   vh, nullptr, (int)NE);
    k_wT<<<dim3(WN / 256), b256, 0, stream>>>(Wq, WqTh, WqTl, 1);
    k_wT<<<dim3(WN / 256), b256, 0, stream>>>(Wk, WkTh, WkTl, 1);
    k_wT<<<dim3(WN / 256), b256, 0, stream>>>(Wv, WvTh, nullptr, 1);
    k_wT<<<dim3(WN / 256), b256, 0, stream>>>(Wo, WoTh, nullptr, 0);

    dim3 gg(8, 32);   // N/128, M/128
    k_gemm<1, 2><<<gg, b256, 0, stream>>>(qh, ql, WqTh, WqTl, bq, Qh, Ql, nullptr, Mrows, Ee, Ee);
    k_gemm<1, 2><<<gg, b256, 0, stream>>>(kh, kl, WkTh, WkTl, bk, Kh, Kl, nullptr, Mrows, Ee, Ee);
    k_gemm<0, 1><<<gg, b256, 0, stream>>>(vh, nullptr, WvTh, nullptr, bv, Vt, nullptr, nullptr, Mrows, Ee, Ee);

    k_attn<<<dim3(Ss / 64, Bb * Hh), b256, 0, stream>>>(Qh, Ql, Kh, Kl, Vt, ctx);

    k_gemm<0, 0><<<gg, b256, 0, stream>>>(ctx, nullptr, WoTh, nullptr, bo, nullptr, nullptr, (float*)d_out, Mrows, Ee, Ee);
}